// Round 6
// baseline (1290.438 us; speedup 1.0000x reference)
//
#include <hip/hip_runtime.h>
#include <hip/hip_cooperative_groups.h>

namespace cg = cooperative_groups;

// Problem constants
constexpr int Bc  = 4;
constexpr int Sc  = 384;
constexpr int Dc  = 300;
constexpr int Ec  = 50;
constexpr int HDc = 150;          // D / L
constexpr int WHC = 350;          // Wh row length
constexpr int MT  = Bc * Sc;      // 1536 flat rows

// ---------------------------------------------------------------------------
// adj tile: 64 rows x 50, LDS-staged coalesced float4 loads, 4 lanes/row
// reduce. A0[g] = rowsum/E ; wadj[g] = weighted rowsum (we colsums in wec).
// ---------------------------------------------------------------------------
__device__ __forceinline__ void adj_tile(float* tile, const float* wec,
    const float* __restrict__ adjp, int tau,
    float* __restrict__ A0, float* __restrict__ wadj)
{
    __syncthreads();                       // protect LDS from previous task
    int t = threadIdx.x;
    const float4* p4 = (const float4*)(adjp + (long)tau * 3200);
    for (int i = t; i < 800; i += 256) {
        float4 v = p4[i];
        int e = 4 * i;
        tile[(e/50)*51 + (e%50)]         = v.x;
        tile[((e+1)/50)*51 + ((e+1)%50)] = v.y;
        tile[((e+2)/50)*51 + ((e+2)%50)] = v.z;
        tile[((e+3)/50)*51 + ((e+3)%50)] = v.w;
    }
    __syncthreads();
    int r = t >> 2, q = t & 3;
    int h0 = q * 13, h1 = (q == 3) ? 50 : h0 + 13;
    const float* row = tile + r * 51;
    float s = 0.f, w = 0.f;
    for (int i = h0; i < h1; ++i) { float v = row[i]; s += v; w += v * wec[i]; }
    s += __shfl_xor(s, 1); w += __shfl_xor(w, 1);
    s += __shfl_xor(s, 2); w += __shfl_xor(w, 2);
    if (q == 0) {
        int g = tau * 64 + r;
        A0[g]   = s * (1.0f / Ec);
        wadj[g] = w;
    }
}

// ---------------------------------------------------------------------------
// tb_gemm: 16 rows x 64 cols tile; B is a row-major (N x K) weight matrix,
// transposed through LDS in 32-k chunks (stride 65 -> conflict-free both ways).
// A-row loads wave-uniform (scalar pipe). WCAT: B = [W0 | W1a | Wout] concat.
//   C[g,c] = sum_k A[g,k]*W[c,k] [+ Dm[g,c]] [+ bias[c]]
// ---------------------------------------------------------------------------
template<int WCAT, int HASD, int HASB>
__device__ __forceinline__ void tb_gemm(
    float* bs, int rt, int ct,
    const float* __restrict__ A, int lda,
    const float* __restrict__ Wr, int ldw,
    const float* __restrict__ Wb2, const float* __restrict__ Wb3,
    const float* __restrict__ Dm, int ldd,
    const float* __restrict__ bias,
    float* __restrict__ C, int ldc, int N, int K)
{
    int tid = threadIdx.x;
    int cc = tid & 63, wq = tid >> 6;
    int r0 = rt * 16, c0 = ct * 64;
    int cg_ = c0 + cc;
    bool cok = cg_ < N;
    float acc[4] = {0.f, 0.f, 0.f, 0.f};

    for (int k0 = 0; k0 < K; k0 += 32) {
        int kmax = min(32, K - k0);
        __syncthreads();
        #pragma unroll
        for (int p = 0; p < 8; ++p) {
            int idx = tid + p * 256;
            int kk = idx & 31, c2 = idx >> 5;
            int n = c0 + c2, k = k0 + kk;
            float v = 0.f;
            if (n < N && k < K) {
                if constexpr (WCAT) {
                    if (n < HDc)        v = Wr[n * Dc + k];
                    else if (n < 2*HDc) v = Wb2[(n - HDc) * (Dc + HDc) + k];
                    else                v = Wb3[(n - 2*HDc) * Dc + k];
                } else {
                    v = Wr[(long)n * ldw + k];
                }
            }
            bs[kk * 65 + c2] = v;
        }
        __syncthreads();
        for (int kk = 0; kk < kmax; ++kk) {
            float bv = bs[kk * 65 + cc];
            #pragma unroll
            for (int i = 0; i < 4; ++i) {
                float a = A[(long)(r0 + wq*4 + i) * lda + k0 + kk];
                acc[i] = fmaf(a, bv, acc[i]);
            }
        }
    }
    if (cok) {
        #pragma unroll
        for (int i = 0; i < 4; ++i) {
            long g = r0 + wq*4 + i;
            float v = acc[i];
            if constexpr (HASD) v += Dm[g * ldd + cg_];
            if constexpr (HASB) v += bias[cg_];
            C[g * ldc + cg_] = v;
        }
    }
}

// ---------------------------------------------------------------------------
// sk_gemm: split-K 4-way (wave w owns 96 of K=384), 4 rows x 64 cols tile.
// A flat [1536 x 384] (A0 or wadj); B k-major inside R (ld 600), batch-local;
// epilogue: + P + 2*bias, relu. A1M: a = wadj + s1[k] + s2[g] + sbh, /E via bv.
// ---------------------------------------------------------------------------
template<int A1M>
__device__ __forceinline__ void sk_gemm(
    float* red, int rt, int ct,
    const float* __restrict__ A, const float* __restrict__ Bt,
    const float* __restrict__ bias, const float* __restrict__ s12,
    float sbh, float* __restrict__ C, int ldc, int N)
{
    __syncthreads();                       // protect red from previous task
    int tid = threadIdx.x, wave = tid >> 6, lane = tid & 63;
    int g0 = rt * 4;
    int b = g0 / Sc;
    const float* Ab = A + (long)g0 * Sc;
    const float* Bb = Bt + (long)b * Sc * 600;
    int c = ct * 64 + lane;
    bool cok = c < N;
    constexpr float invE = 1.0f / Ec;

    float tr[4];
    const float* s1base = nullptr;
    if constexpr (A1M) {
        s1base = s12 + 2L * b * Sc;
        #pragma unroll
        for (int r = 0; r < 4; ++r) tr[r] = s12[2*(g0 + r) + 1] + sbh;
    }

    float acc[4] = {0.f, 0.f, 0.f, 0.f};
    int kb = wave * 96;
    for (int k = kb; k < kb + 96; k += 4) {
        float bv[4];
        #pragma unroll
        for (int j = 0; j < 4; ++j)
            bv[j] = cok ? Bb[(long)(k + j) * 600 + c] : 0.f;
        #pragma unroll
        for (int j = 0; j < 4; ++j) {
            float bvj = bv[j];
            float s1k = 0.f;
            if constexpr (A1M) { s1k = s1base[2*(k + j)]; bvj *= invE; }
            #pragma unroll
            for (int r = 0; r < 4; ++r) {
                float a = Ab[(long)r * Sc + k + j];
                if constexpr (A1M) a += s1k + tr[r];
                acc[r] = fmaf(a, bvj, acc[r]);
            }
        }
    }
    #pragma unroll
    for (int r = 0; r < 4; ++r) red[wave*256 + r*64 + lane] = acc[r];
    __syncthreads();
    int row = tid >> 6, col = tid & 63;
    int cg_ = ct * 64 + col;
    if (cg_ < N) {
        long g = g0 + row;
        float v = red[tid] + red[256 + tid] + red[512 + tid] + red[768 + tid];
        v += Bt[g * 600 + cg_] + 2.0f * bias[cg_];
        v = fmaxf(v, 0.f);
        C[g * ldc + cg_] = v;
    }
}

// ---------------------------------------------------------------------------
// s12 task: 4 rows per unit, wave per row. s12[2g]=G0[g]·w1cs, s12[2g+1]=·w2cs
// ---------------------------------------------------------------------------
__device__ __forceinline__ void s12_rows(const float* __restrict__ G,
    const float* __restrict__ sm, float* __restrict__ s12, int u)
{
    int wave = threadIdx.x >> 6, lane = threadIdx.x & 63;
    int g = u * 4 + wave;
    const float* gp = G + (long)g * Dc;
    float a = 0.f, c = 0.f;
    #pragma unroll
    for (int h0 = 0; h0 < HDc; h0 += 64) {
        int h = h0 + lane;
        if (h < HDc) { float v = gp[h]; a += v * sm[64 + h]; c += v * sm[224 + h]; }
    }
    #pragma unroll
    for (int off = 32; off; off >>= 1) {
        a += __shfl_down(a, off);
        c += __shfl_down(c, off);
    }
    if (lane == 0) { s12[2*g] = a; s12[2*g + 1] = c; }
}

// ---------------------------------------------------------------------------
// mega: the whole model, one cooperative launch, 5 stages with grid.sync().
// ---------------------------------------------------------------------------
__global__ __launch_bounds__(256, 4)
void mega(const float* __restrict__ adj, const float* __restrict__ X,
          const float* __restrict__ W0, const float* __restrict__ b0,
          const float* __restrict__ W1, const float* __restrict__ b1,
          const float* __restrict__ Wh, const float* __restrict__ bh,
          const float* __restrict__ Wout, const float* __restrict__ bout,
          float* __restrict__ out,
          float* __restrict__ A0, float* __restrict__ wadj,
          float* __restrict__ R, float* __restrict__ Gbuf,
          float* __restrict__ s12, float* __restrict__ sm)
{
    __shared__ float lds[3328];            // 13.3 KB: tile(3264) | wec(50)
    float* wec = lds + 3264;
    cg::grid_group grid = cg::this_grid();
    int bid = blockIdx.x;
    int gd  = gridDim.x;

    // per-block we colsums (for adj task)
    if (threadIdx.x < Ec) {
        float s = 0.f;
        for (int e = 0; e < Ec; ++e) s += Wh[e * WHC + threadIdx.x];
        wec[threadIdx.x] = s;
    }
    // block 0: w1/w2 colsums + sum(bh) into sm (needed from stage C on)
    if (bid == 0) {
        for (int idx = threadIdx.x; idx < 301; idx += 256) {
            if (idx < 150) {
                float s = 0.f;
                for (int e = 0; e < Ec; ++e) s += Wh[e*WHC + Ec + idx];
                sm[64 + idx] = s;
            } else if (idx < 300) {
                int h = idx - 150;
                float s = 0.f;
                for (int e = 0; e < Ec; ++e) s += Wh[e*WHC + Ec + HDc + h];
                sm[224 + h] = s;
            } else {
                float s = 0.f;
                for (int e = 0; e < Ec; ++e) s += bh[e];
                sm[384] = s;
            }
        }
    }

    // ---- Stage A: adj reduction (9216 units) interleaved with
    //      R = X @ [W0|W1a|Wout]^T (960 tiles, every w%10==9, w<9600) ----
    for (int w = bid; w < 10176; w += gd) {
        if ((w % 10) == 9 && w < 9600) {
            int q = w / 10;                // R tile id in [0,960)
            tb_gemm<1,0,0>(lds, q / 10, q % 10,
                           X, Dc, W0, 0, W1, Wout,
                           nullptr, 0, nullptr, R, 600, 600, Dc);
        } else {
            int aidx = w - min((w + 1) / 10, 960);
            adj_tile(lds, wec, adj, aidx, A0, wadj);
        }
    }
    grid.sync();

    // ---- Stage B: G0 = relu(A0 @ P0 + P0 + 2*b0)  (1152 tiles) ----
    for (int u = bid; u < 1152; u += gd)
        sk_gemm<0>(lds, u / 3, u % 3, A0, R, b0, nullptr, 0.f, Gbuf, Dc, HDc);
    grid.sync();

    // ---- Stage C: P1 = Q1 + G0 @ W1b^T (288 tiles) + s12 (384 units) ----
    for (int u = bid; u < 672; u += gd) {
        if (u < 288) {
            tb_gemm<0,1,0>(lds, u / 3, u % 3,
                           Gbuf, Dc, W1 + Dc, Dc + HDc, nullptr, nullptr,
                           R + HDc, 600, nullptr, R + HDc, 600, HDc, HDc);
        } else {
            s12_rows(Gbuf, sm, s12, u - 288);
        }
    }
    grid.sync();

    // ---- Stage D: G1 = relu(A1 @ P1 + P1 + 2*b1), A1 fused (1152 tiles) ----
    {
        float sbh = sm[384];
        for (int u = bid; u < 1152; u += gd)
            sk_gemm<1>(lds, u / 3, u % 3, wadj, R + HDc, b1, s12, sbh,
                       Gbuf + HDc, Dc, HDc);
    }
    grid.sync();

    // ---- Stage E: out = [G0|G1] @ Wout^T + X@Wout^T + bout (480 tiles) ----
    for (int u = bid; u < 480; u += gd)
        tb_gemm<0,1,1>(lds, u / 5, u % 5,
                       Gbuf, Dc, Wout, Dc, nullptr, nullptr,
                       R + 2*HDc, 600, bout, out, Dc, Dc, Dc);
}

extern "C" void kernel_launch(void* const* d_in, const int* in_sizes, int n_in,
                              void* d_out, int out_size, void* d_ws, size_t ws_size,
                              hipStream_t stream) {
    const float* adj  = (const float*)d_in[0];
    const float* X    = (const float*)d_in[1];
    const float* W0   = (const float*)d_in[2];
    const float* b0   = (const float*)d_in[3];
    const float* W1   = (const float*)d_in[4];
    const float* b1   = (const float*)d_in[5];
    const float* Wh   = (const float*)d_in[6];
    const float* bh   = (const float*)d_in[7];
    const float* Wout = (const float*)d_in[8];
    const float* bout = (const float*)d_in[9];
    float* out = (float*)d_out;

    // workspace layout (floats)
    float* ws   = (float*)d_ws;
    float* sm   = ws;                          // 512
    float* A0   = sm + 512;                    // 1536 x 384
    float* wadj = A0 + MT * Sc;                // 1536 x 384
    float* R    = wadj + MT * Sc;              // 1536 x 600: [P0 | Q1->P1 | X@Wout^T]
    float* Gbuf = R + (long)MT * 600;          // 1536 x 300: [G0 | G1]
    float* s12  = Gbuf + (long)MT * Dc;        // 1536 x 2 interleaved (s1,s2)

    // cooperative grid size: co-resident capacity (deterministic queries)
    int dev = 0;
    hipGetDevice(&dev);
    int numCU = 256;
    hipDeviceGetAttribute(&numCU, hipDeviceAttributeMultiprocessorCount, dev);
    int nb = 0;
    hipOccupancyMaxActiveBlocksPerMultiprocessor(&nb, (const void*)mega, 256, 0);
    if (nb < 1) nb = 1;
    long grid = (long)numCU * nb;
    if (grid > 2048) grid = 2048;

    void* args[] = {&adj, &X, &W0, &b0, &W1, &b1, &Wh, &bh, &Wout, &bout,
                    &out, &A0, &wadj, &R, &Gbuf, &s12, &sm};
    hipLaunchCooperativeKernel((const void*)mega, dim3((int)grid), dim3(256),
                               args, 0, stream);
}

// Round 7
// 261.146 us; speedup vs baseline: 4.9414x; 4.9414x over previous
//
#include <hip/hip_runtime.h>

// Problem constants
constexpr int Bc  = 4;
constexpr int Sc  = 384;
constexpr int Dc  = 300;
constexpr int Ec  = 50;
constexpr int HDc = 150;          // D / L
constexpr int WHC = 350;          // Wh row length

typedef __attribute__((ext_vector_type(8))) short bf16x8;
typedef __attribute__((ext_vector_type(4))) float f32x4;

__device__ __forceinline__ short f2bf(float x) {
    union { float f; unsigned u; } v; v.f = x;
    unsigned r = (v.u + 0x7FFFu + ((v.u >> 16) & 1u)) >> 16;
    return (short)r;
}

// ---------------------------------------------------------------------------
// prep: column sums of Wh_e, Wh_1, Wh_2 and sum(bh) into sm
// layout: [0..49] we, [64..213] w1, [224..373] w2, [384] sum(bh)
// ---------------------------------------------------------------------------
__global__ void prep_kernel(const float* __restrict__ Wh,
                            const float* __restrict__ bh,
                            float* __restrict__ sm) {
    int t = threadIdx.x;  // 512 threads
    if (t < Ec) {
        float s = 0.f;
        for (int e = 0; e < Ec; ++e) s += Wh[e*WHC + t];
        sm[t] = s;
    } else if (t >= 64 && t < 64 + HDc) {
        int h = t - 64;
        float s = 0.f;
        for (int e = 0; e < Ec; ++e) s += Wh[e*WHC + Ec + h];
        sm[t] = s;
    } else if (t >= 224 && t < 224 + HDc) {
        int h = t - 224;
        float s = 0.f;
        for (int e = 0; e < Ec; ++e) s += Wh[e*WHC + Ec + HDc + h];
        sm[t] = s;
    } else if (t == 384) {
        float s = 0.f;
        for (int e = 0; e < Ec; ++e) s += bh[e];
        sm[t] = s;
    }
}

// ---------------------------------------------------------------------------
// reduce_adj2 (round-2 proven): one coalesced pass over adj (B,S,S,E).
//   A0[row] = (sum_e adj)/E ; wadj[row] = sum_e adj*we_colsum[e]
// ---------------------------------------------------------------------------
__global__ __launch_bounds__(256)
void reduce_adj2(const float* __restrict__ adj, const float* __restrict__ sm,
                 float* __restrict__ A0, float* __restrict__ wadj) {
    __shared__ float wec[64];
    __shared__ float tile[256 * 51];
    int t = threadIdx.x;
    if (t < Ec) wec[t] = sm[t];
    long base = (long)blockIdx.x * (256 * 50);
    const float4* p4 = (const float4*)(adj + base);
    for (int i = t; i < 3200; i += 256) {
        float4 v = p4[i];
        int e = 4 * i;
        tile[(e/50)*51 + (e%50)]         = v.x;
        tile[((e+1)/50)*51 + ((e+1)%50)] = v.y;
        tile[((e+2)/50)*51 + ((e+2)%50)] = v.z;
        tile[((e+3)/50)*51 + ((e+3)%50)] = v.w;
    }
    __syncthreads();
    const float* row = tile + t * 51;
    float s = 0.f, w = 0.f;
    #pragma unroll
    for (int i = 0; i < 50; ++i) { float v = row[i]; s += v; w += v * wec[i]; }
    int r = blockIdx.x * 256 + t;
    A0[r]   = s * (1.0f / Ec);
    wadj[r] = w;
}

// ---------------------------------------------------------------------------
// mgemm: bf16 MFMA GEMM, 256 thr = 4 waves, 32x32 C tile (wave = one 16x16),
// K-step 32 (one mfma_f32_16x16x32_bf16 per wave per step), fp32->bf16 in
// the LDS stager, register-prefetch double buffer. LDS rows stride 40
// (80 B, 16B-aligned b128 frag reads).
//   C[m,n] = sum_k A[m,k]*B[k,n] [+ Dm] [+ bscale*bias] [relu]
// BSRC 0: B k-major (ld ldb, batched via sB)
// BSRC 1: B row-major weight N x K (ld ldb)
// BSRC 2: B = concat cols [W0 | W1[:,0:300] | Wout] row-major (K=300)
// A1M: A element = (wadj + s1[k] + s2[m] + sbh)/E from s12/sm
// ---------------------------------------------------------------------------
template<int BSRC, int A1M, int HASD, int HASB, int RELU>
__global__ __launch_bounds__(256)
void mgemm(const float* __restrict__ A, int lda, long sA,
           const float* __restrict__ Bw, int ldb, long sB,
           const float* __restrict__ W1a, const float* __restrict__ WoutP,
           const float* __restrict__ Dm, int ldd, long sD,
           const float* __restrict__ bias, float bscale,
           const float* __restrict__ s12, const float* __restrict__ sm,
           float* __restrict__ C, int ldc, long sC,
           int M, int N, int K)
{
    const int b = blockIdx.z;
    const float* Ap = A + (long)b * sA;
    const float* Bp = Bw + (long)b * sB;
    const float* Dp = Dm + (long)b * sD;
    float* Cp = C + (long)b * sC;

    __shared__ short As[32 * 40];
    __shared__ short Bs[32 * 40];

    const int tid  = threadIdx.x;
    const int wave = tid >> 6, lane = tid & 63;
    const int wm = wave & 1, wn = wave >> 1;
    const int lm = lane & 15, quad = lane >> 4;
    const int m0 = blockIdx.y * 32, n0 = blockIdx.x * 32;

    // staging maps
    const int srow = tid >> 3;           // 0..31
    const int sk   = (tid & 7) * 4;      // 0,4,..,28
    const int nc   = tid & 31;           // BSRC0 B map
    const int kr   = tid >> 5;           // 0..7

    float sbh = 0.f; const float* s1p = nullptr; float s2v = 0.f;
    if constexpr (A1M) {
        sbh = sm[384];
        s1p = s12 + 2L * Sc * b;
        s2v = s1p[2 * (m0 + srow) + 1];
    }

    float ra[4], rb[4];

    auto stageA = [&](int k0) {
        int am = m0 + srow;
        int kb = k0 + sk;
        if constexpr (A1M) {
            float4 v = *(const float4*)(Ap + (long)am * lda + kb);
            const float* vp = (const float*)&v;
            #pragma unroll
            for (int j = 0; j < 4; ++j)
                ra[j] = (vp[j] + s1p[2 * (kb + j)] + s2v + sbh) * (1.0f / Ec);
        } else {
            if (kb + 3 < K) {
                float4 v = *(const float4*)(Ap + (long)am * lda + kb);
                ra[0] = v.x; ra[1] = v.y; ra[2] = v.z; ra[3] = v.w;
            } else {
                #pragma unroll
                for (int j = 0; j < 4; ++j) {
                    int k = kb + j;
                    ra[j] = (k < K) ? Ap[(long)am * lda + k] : 0.f;
                }
            }
        }
    };

    auto stageB = [&](int k0) {
        if constexpr (BSRC == 0) {
            int n = n0 + nc;
            bool nok = n < N;
            #pragma unroll
            for (int p = 0; p < 4; ++p) {
                int k = k0 + kr + p * 8;
                rb[p] = (nok && k < K) ? Bp[(long)k * ldb + n] : 0.f;
            }
        } else {
            int nr = n0 + srow;
            bool nok = nr < N;
            const float* wp = Bp; int ld = ldb; int nn = nr;
            if constexpr (BSRC == 2) {
                if (nr < 150)      { wp = Bp;    ld = 300; nn = nr; }
                else if (nr < 300) { wp = W1a;   ld = 450; nn = nr - 150; }
                else               { wp = WoutP; ld = 300; nn = nr - 300; }
            }
            #pragma unroll
            for (int p = 0; p < 2; ++p) {
                int k = k0 + sk + 2 * p;
                if (nok && k + 1 < K) {
                    float2 v = *(const float2*)(wp + (long)nn * ld + k);
                    rb[2*p] = v.x; rb[2*p + 1] = v.y;
                } else {
                    rb[2*p]     = (nok && k < K)     ? wp[(long)nn * ld + k]     : 0.f;
                    rb[2*p + 1] = (nok && k + 1 < K) ? wp[(long)nn * ld + k + 1] : 0.f;
                }
            }
        }
    };

    auto stash = [&]() {
        #pragma unroll
        for (int j = 0; j < 4; ++j) As[srow * 40 + sk + j] = f2bf(ra[j]);
        if constexpr (BSRC == 0) {
            #pragma unroll
            for (int p = 0; p < 4; ++p) Bs[nc * 40 + kr + p * 8] = f2bf(rb[p]);
        } else {
            #pragma unroll
            for (int j = 0; j < 4; ++j) Bs[srow * 40 + sk + j] = f2bf(rb[j]);
        }
    };

    f32x4 acc = {0.f, 0.f, 0.f, 0.f};

    stageA(0); stageB(0);
    for (int k0 = 0; k0 < K; k0 += 32) {
        __syncthreads();
        stash();
        __syncthreads();
        if (k0 + 32 < K) { stageA(k0 + 32); stageB(k0 + 32); }
        bf16x8 af  = *(const bf16x8*)(As + (wm * 16 + lm) * 40 + quad * 8);
        bf16x8 bfv = *(const bf16x8*)(Bs + (wn * 16 + lm) * 40 + quad * 8);
        acc = __builtin_amdgcn_mfma_f32_16x16x32_bf16(af, bfv, acc, 0, 0, 0);
    }

    int cn = n0 + wn * 16 + lm;
    if (cn < N) {
        #pragma unroll
        for (int r = 0; r < 4; ++r) {
            int cm = m0 + wm * 16 + quad * 4 + r;
            if (cm < M) {
                float v = acc[r];
                if constexpr (HASD) v += Dp[(long)cm * ldd + cn];
                if constexpr (HASB) v += bscale * bias[cn];
                if constexpr (RELU) v = fmaxf(v, 0.f);
                Cp[(long)cm * ldc + cn] = v;
            }
        }
    }
}

// ---------------------------------------------------------------------------
// s12k: wave per row. s12[2g] = G0[g]·w1cs, s12[2g+1] = G0[g]·w2cs
// (G0 = Gbuf cols 0..149, ld 300)
// ---------------------------------------------------------------------------
__global__ __launch_bounds__(256)
void s12k(const float* __restrict__ G, const float* __restrict__ sm,
          float* __restrict__ s12) {
    int wave = threadIdx.x >> 6, lane = threadIdx.x & 63;
    int g = blockIdx.x * 4 + wave;
    const float* gp = G + (long)g * Dc;
    float a = 0.f, c = 0.f;
    #pragma unroll
    for (int h0 = 0; h0 < HDc; h0 += 64) {
        int h = h0 + lane;
        if (h < HDc) { float v = gp[h]; a += v * sm[64 + h]; c += v * sm[224 + h]; }
    }
    #pragma unroll
    for (int off = 32; off; off >>= 1) {
        a += __shfl_down(a, off);
        c += __shfl_down(c, off);
    }
    if (lane == 0) { s12[2*g] = a; s12[2*g + 1] = c; }
}

extern "C" void kernel_launch(void* const* d_in, const int* in_sizes, int n_in,
                              void* d_out, int out_size, void* d_ws, size_t ws_size,
                              hipStream_t stream) {
    const float* adj  = (const float*)d_in[0];
    const float* X    = (const float*)d_in[1];
    const float* W0   = (const float*)d_in[2];
    const float* b0   = (const float*)d_in[3];
    const float* W1   = (const float*)d_in[4];
    const float* b1   = (const float*)d_in[5];
    const float* Wh   = (const float*)d_in[6];
    const float* bh   = (const float*)d_in[7];
    const float* Wout = (const float*)d_in[8];
    const float* bout = (const float*)d_in[9];
    float* out = (float*)d_out;

    // workspace layout (floats)
    float* ws   = (float*)d_ws;
    float* sm   = ws;                          // 512
    float* A0   = sm + 512;                    // 1536 x 384
    float* wadj = A0 + Bc * Sc * Sc;           // 1536 x 384
    float* R    = wadj + Bc * Sc * Sc;         // 1536 x 600: [P0 | P1 | X@Wout^T]
    float* Gbuf = R + (long)Bc * Sc * 600;     // 1536 x 300: [G0 | G1]
    float* s12  = Gbuf + (long)Bc * Sc * Dc;   // 1536 x 2 interleaved

    const int MT = Bc * Sc;                    // 1536
    const long AS = (long)Sc * Sc;             // adj batch stride
    const long RS = (long)Sc * 600;            // R batch stride (rows)
    const long GS = (long)Sc * Dc;             // Gbuf batch stride

    // 1) weight column sums + sum(bh)
    prep_kernel<<<1, 512, 0, stream>>>(Wh, bh, sm);

    // 2) one HBM pass over adj
    reduce_adj2<<<(Bc*Sc*Sc) / 256, 256, 0, stream>>>(adj, sm, A0, wadj);

    // 3) R = X @ [W0 | W1a | Wout]^T  (M=1536, N=600, K=300)
    mgemm<2,0,0,0,0><<<dim3(19, 48, 1), 256, 0, stream>>>(
        X, Dc, 0, W0, 300, 0, W1, Wout,
        nullptr, 0, 0, nullptr, 0.f, nullptr, nullptr,
        R, 600, 0, MT, 600, Dc);

    // 4) G0 = relu(A0 @ P0 + P0 + 2*b0)  (batched; M=384, N=150, K=384)
    mgemm<0,0,1,1,1><<<dim3(5, 12, Bc), 256, 0, stream>>>(
        A0, Sc, AS, R, 600, RS, nullptr, nullptr,
        R, 600, RS, b0, 2.0f, nullptr, nullptr,
        Gbuf, Dc, GS, Sc, HDc, Sc);

    // 5) s1/s2 row reductions of G0
    s12k<<<MT / 4, 256, 0, stream>>>(Gbuf, sm, s12);

    // 6) P1 = Q1 + G0 @ W1b^T  (flat; M=1536, N=150, K=150; in-place R[:,150:300])
    mgemm<1,0,1,0,0><<<dim3(5, 48, 1), 256, 0, stream>>>(
        Gbuf, Dc, 0, W1 + Dc, Dc + HDc, 0, nullptr, nullptr,
        R + HDc, 600, 0, nullptr, 0.f, nullptr, nullptr,
        R + HDc, 600, 0, MT, HDc, HDc);

    // 7) G1 = relu(A1 @ P1 + P1 + 2*b1); A1 fused from wadj+s12 (batched)
    mgemm<0,1,1,1,1><<<dim3(5, 12, Bc), 256, 0, stream>>>(
        wadj, Sc, AS, R + HDc, 600, RS, nullptr, nullptr,
        R + HDc, 600, RS, b1, 2.0f, s12, sm,
        Gbuf + HDc, Dc, GS, Sc, HDc, Sc);

    // 8) out = [G0|G1] @ Wout^T + X@Wout^T + bout  (M=1536, N=300, K=300)
    mgemm<1,0,1,1,0><<<dim3(10, 48, 1), 256, 0, stream>>>(
        Gbuf, Dc, 0, Wout, Dc, 0, nullptr, nullptr,
        R + 2*HDc, 600, 0, bout, 1.0f, nullptr, nullptr,
        out, Dc, 0, MT, Dc, Dc);
}

// Round 8
// 244.644 us; speedup vs baseline: 5.2748x; 1.0675x over previous
//
#include <hip/hip_runtime.h>

// Problem constants
constexpr int Bc  = 4;
constexpr int Sc  = 384;
constexpr int Dc  = 300;
constexpr int Ec  = 50;
constexpr int HDc = 150;          // D / L
constexpr int WHC = 350;          // Wh row length

typedef __attribute__((ext_vector_type(8))) short bf16x8;
typedef __attribute__((ext_vector_type(4))) float f32x4;

__device__ __forceinline__ short f2bf(float x) {
    union { float f; unsigned u; } v; v.f = x;
    unsigned r = (v.u + 0x7FFFu + ((v.u >> 16) & 1u)) >> 16;
    return (short)r;
}

// ---------------------------------------------------------------------------
// prep: column sums of Wh_e, Wh_1, Wh_2 and sum(bh) into sm
// layout: [0..49] we, [64..213] w1, [224..373] w2, [384] sum(bh)
// ---------------------------------------------------------------------------
__global__ void prep_kernel(const float* __restrict__ Wh,
                            const float* __restrict__ bh,
                            float* __restrict__ sm) {
    int t = threadIdx.x;  // 512 threads
    if (t < Ec) {
        float s = 0.f;
        for (int e = 0; e < Ec; ++e) s += Wh[e*WHC + t];
        sm[t] = s;
    } else if (t >= 64 && t < 64 + HDc) {
        int h = t - 64;
        float s = 0.f;
        for (int e = 0; e < Ec; ++e) s += Wh[e*WHC + Ec + h];
        sm[t] = s;
    } else if (t >= 224 && t < 224 + HDc) {
        int h = t - 224;
        float s = 0.f;
        for (int e = 0; e < Ec; ++e) s += Wh[e*WHC + Ec + HDc + h];
        sm[t] = s;
    } else if (t == 384) {
        float s = 0.f;
        for (int e = 0; e < Ec; ++e) s += bh[e];
        sm[t] = s;
    }
}

// ---------------------------------------------------------------------------
// reduce_adj3: 64-row tiles (13 KB LDS -> 8 blocks/CU), all global loads
// issued back-to-back (MLP), 4-lane/row reduce + shfl_xor.
//   A0[g] = (sum_e adj[g,:])/E ; wadj[g] = sum_e adj[g,e]*we[e]
// ---------------------------------------------------------------------------
__global__ __launch_bounds__(256)
void reduce_adj3(const float* __restrict__ adj, const float* __restrict__ sm,
                 float* __restrict__ A0, float* __restrict__ wadj) {
    __shared__ float tile[64 * 51];     // 13056 B
    __shared__ float wec[64];
    int t = threadIdx.x;
    if (t < Ec) wec[t] = sm[t];

    long base = (long)blockIdx.x * 3200;          // 64 rows * 50 floats
    const float4* p4 = (const float4*)(adj + base);
    // 800 float4 per tile: 3 full rounds + 32-thread tail, loads all in flight
    float4 v0 = p4[t];
    float4 v1 = p4[t + 256];
    float4 v2 = p4[t + 512];
    float4 v3 = {0.f, 0.f, 0.f, 0.f};
    if (t < 32) v3 = p4[t + 768];

    auto scat = [&](int i, const float4& v) {
        const float* vp = (const float*)&v;
        #pragma unroll
        for (int j = 0; j < 4; ++j) {
            int e = 4 * i + j;
            tile[(e / 50) * 51 + (e % 50)] = vp[j];
        }
    };
    scat(t, v0);
    scat(t + 256, v1);
    scat(t + 512, v2);
    if (t < 32) scat(t + 768, v3);
    __syncthreads();

    int r = t >> 2, q = t & 3;
    int h0 = q * 13, h1 = (q == 3) ? 50 : h0 + 13;
    const float* row = tile + r * 51;
    float s = 0.f, w = 0.f;
    for (int i = h0; i < h1; ++i) { float v = row[i]; s += v; w += v * wec[i]; }
    s += __shfl_xor(s, 1); w += __shfl_xor(w, 1);
    s += __shfl_xor(s, 2); w += __shfl_xor(w, 2);
    if (q == 0) {
        int g = blockIdx.x * 64 + r;
        A0[g]   = s * (1.0f / Ec);
        wadj[g] = w;
    }
}

// ---------------------------------------------------------------------------
// mgemm: bf16 MFMA GEMM, 256 thr = 4 waves, 32x32 C tile, BK=64 (two
// mfma_f32_16x16x32_bf16 per wave per iter), fp32->bf16 fused into LDS
// staging, register-prefetch double buffer. LDS row stride 72 shorts.
// BSRC 0: B k-major (ld ldb, batched sB). 1: B row-major N x K (ld ldb).
// 2: B = concat [W0 | W1[:,0:300] | Wout] row-major, K=300.
// A1M: A element = (wadj + s1[k] + s2[m] + sbh)/E from s12/sm
// ---------------------------------------------------------------------------
template<int BSRC, int A1M, int HASD, int HASB, int RELU>
__global__ __launch_bounds__(256)
void mgemm(const float* __restrict__ A, int lda, long sA,
           const float* __restrict__ Bw, int ldb, long sB,
           const float* __restrict__ W1a, const float* __restrict__ WoutP,
           const float* __restrict__ Dm, int ldd, long sD,
           const float* __restrict__ bias, float bscale,
           const float* __restrict__ s12, const float* __restrict__ sm,
           float* __restrict__ C, int ldc, long sC,
           int M, int N, int K)
{
    const int b = blockIdx.z;
    const float* Ap = A + (long)b * sA;
    const float* Bp = Bw + (long)b * sB;
    const float* Dp = Dm + (long)b * sD;
    float* Cp = C + (long)b * sC;

    __shared__ short As[32 * 72];
    __shared__ short Bs[32 * 72];

    const int tid  = threadIdx.x;
    const int wave = tid >> 6, lane = tid & 63;
    const int wm = wave & 1, wn = wave >> 1;
    const int lm = lane & 15, quad = lane >> 4;
    const int m0 = blockIdx.y * 32, n0 = blockIdx.x * 32;

    const int srow = tid >> 3;           // 0..31 (A rows / B n-rows)
    const int sk   = (tid & 7) * 8;      // 0,8,..,56
    const int nc   = tid & 31;           // BSRC0 n
    const int kr   = tid >> 5;           // BSRC0 k base 0..7

    float sbh = 0.f; const float* s1p = nullptr; float s2v = 0.f;
    if constexpr (A1M) {
        sbh = sm[384];
        s1p = s12 + 2L * Sc * b;
        s2v = s1p[2 * (m0 + srow) + 1];
    }

    float ra[8], rb[8];

    auto stageA = [&](int k0) {
        int am = m0 + srow;
        int kb = k0 + sk;
        if constexpr (A1M) {             // K=384 exact, no masks
            float4 u = *(const float4*)(Ap + (long)am * lda + kb);
            float4 w = *(const float4*)(Ap + (long)am * lda + kb + 4);
            const float* up = (const float*)&u;
            const float* wp = (const float*)&w;
            #pragma unroll
            for (int j = 0; j < 4; ++j) {
                ra[j]     = (up[j] + s1p[2*(kb + j)]     + s2v + sbh) * (1.0f/Ec);
                ra[4 + j] = (wp[j] + s1p[2*(kb + 4 + j)] + s2v + sbh) * (1.0f/Ec);
            }
        } else {
            if (kb + 7 < K) {
                float4 u = *(const float4*)(Ap + (long)am * lda + kb);
                float4 w = *(const float4*)(Ap + (long)am * lda + kb + 4);
                ra[0]=u.x; ra[1]=u.y; ra[2]=u.z; ra[3]=u.w;
                ra[4]=w.x; ra[5]=w.y; ra[6]=w.z; ra[7]=w.w;
            } else {
                #pragma unroll
                for (int j = 0; j < 8; ++j) {
                    int k = kb + j;
                    ra[j] = (k < K) ? Ap[(long)am * lda + k] : 0.f;
                }
            }
        }
    };

    auto stageB = [&](int k0) {
        if constexpr (BSRC == 0) {       // k-major, K=384 exact here
            int n = n0 + nc;
            bool nok = n < N;
            #pragma unroll
            for (int p = 0; p < 8; ++p) {
                int k = k0 + kr + p * 8;
                rb[p] = nok ? Bp[(long)k * ldb + n] : 0.f;
            }
        } else {
            int nr = n0 + srow;
            bool nok = nr < N;
            const float* wp = Bp; int ld = ldb; int nn = nr;
            if constexpr (BSRC == 2) {
                if (nr < 150)      { wp = Bp;    ld = 300; nn = nr; }
                else if (nr < 300) { wp = W1a;   ld = 450; nn = nr - 150; }
                else               { wp = WoutP; ld = 300; nn = nr - 300; }
            }
            #pragma unroll
            for (int p = 0; p < 4; ++p) {
                int k = k0 + sk + 2 * p;
                if (nok && k + 1 < K) {
                    float2 v = *(const float2*)(wp + (long)nn * ld + k);
                    rb[2*p] = v.x; rb[2*p + 1] = v.y;
                } else {
                    rb[2*p]     = (nok && k < K)     ? wp[(long)nn * ld + k]     : 0.f;
                    rb[2*p + 1] = (nok && k + 1 < K) ? wp[(long)nn * ld + k + 1] : 0.f;
                }
            }
        }
    };

    auto stash = [&]() {
        #pragma unroll
        for (int j = 0; j < 8; ++j) As[srow * 72 + sk + j] = f2bf(ra[j]);
        if constexpr (BSRC == 0) {
            #pragma unroll
            for (int p = 0; p < 8; ++p) Bs[nc * 72 + kr + p * 8] = f2bf(rb[p]);
        } else {
            #pragma unroll
            for (int j = 0; j < 8; ++j) Bs[srow * 72 + sk + j] = f2bf(rb[j]);
        }
    };

    f32x4 acc = {0.f, 0.f, 0.f, 0.f};

    stageA(0); stageB(0);
    for (int k0 = 0; k0 < K; k0 += 64) {
        __syncthreads();
        stash();
        __syncthreads();
        if (k0 + 64 < K) { stageA(k0 + 64); stageB(k0 + 64); }
        {
            bf16x8 a0 = *(const bf16x8*)(As + (wm*16 + lm) * 72 + quad * 8);
            bf16x8 b0 = *(const bf16x8*)(Bs + (wn*16 + lm) * 72 + quad * 8);
            acc = __builtin_amdgcn_mfma_f32_16x16x32_bf16(a0, b0, acc, 0, 0, 0);
            bf16x8 a1 = *(const bf16x8*)(As + (wm*16 + lm) * 72 + 32 + quad * 8);
            bf16x8 b1 = *(const bf16x8*)(Bs + (wn*16 + lm) * 72 + 32 + quad * 8);
            acc = __builtin_amdgcn_mfma_f32_16x16x32_bf16(a1, b1, acc, 0, 0, 0);
        }
    }

    int cn = n0 + wn * 16 + lm;
    if (cn < N) {
        #pragma unroll
        for (int r = 0; r < 4; ++r) {
            int cm = m0 + wm * 16 + quad * 4 + r;
            if (cm < M) {
                float v = acc[r];
                if constexpr (HASD) v += Dp[(long)cm * ldd + cn];
                if constexpr (HASB) v += bscale * bias[cn];
                if constexpr (RELU) v = fmaxf(v, 0.f);
                Cp[(long)cm * ldc + cn] = v;
            }
        }
    }
}

// ---------------------------------------------------------------------------
// s12k: wave per row. s12[2g] = G0[g]·w1cs, s12[2g+1] = G0[g]·w2cs
// ---------------------------------------------------------------------------
__global__ __launch_bounds__(256)
void s12k(const float* __restrict__ G, const float* __restrict__ sm,
          float* __restrict__ s12) {
    int wave = threadIdx.x >> 6, lane = threadIdx.x & 63;
    int g = blockIdx.x * 4 + wave;
    const float* gp = G + (long)g * Dc;
    float a = 0.f, c = 0.f;
    #pragma unroll
    for (int h0 = 0; h0 < HDc; h0 += 64) {
        int h = h0 + lane;
        if (h < HDc) { float v = gp[h]; a += v * sm[64 + h]; c += v * sm[224 + h]; }
    }
    #pragma unroll
    for (int off = 32; off; off >>= 1) {
        a += __shfl_down(a, off);
        c += __shfl_down(c, off);
    }
    if (lane == 0) { s12[2*g] = a; s12[2*g + 1] = c; }
}

extern "C" void kernel_launch(void* const* d_in, const int* in_sizes, int n_in,
                              void* d_out, int out_size, void* d_ws, size_t ws_size,
                              hipStream_t stream) {
    const float* adj  = (const float*)d_in[0];
    const float* X    = (const float*)d_in[1];
    const float* W0   = (const float*)d_in[2];
    const float* b0   = (const float*)d_in[3];
    const float* W1   = (const float*)d_in[4];
    const float* b1   = (const float*)d_in[5];
    const float* Wh   = (const float*)d_in[6];
    const float* bh   = (const float*)d_in[7];
    const float* Wout = (const float*)d_in[8];
    const float* bout = (const float*)d_in[9];
    float* out = (float*)d_out;

    // workspace layout (floats)
    float* ws   = (float*)d_ws;
    float* sm   = ws;                          // 512
    float* A0   = sm + 512;                    // 1536 x 384
    float* wadj = A0 + Bc * Sc * Sc;           // 1536 x 384
    float* R    = wadj + Bc * Sc * Sc;         // 1536 x 600: [P0 | P1 | X@Wout^T]
    float* Gbuf = R + (long)Bc * Sc * 600;     // 1536 x 300: [G0 | G1]
    float* s12  = Gbuf + (long)Bc * Sc * Dc;   // 1536 x 2 interleaved

    const int MT = Bc * Sc;                    // 1536
    const long AS = (long)Sc * Sc;             // adj batch stride
    const long RS = (long)Sc * 600;            // R batch stride (rows)
    const long GS = (long)Sc * Dc;             // Gbuf batch stride

    // 1) weight column sums + sum(bh)
    prep_kernel<<<1, 512, 0, stream>>>(Wh, bh, sm);

    // 2) one HBM pass over adj (64-row tiles, high occupancy)
    reduce_adj3<<<(Bc*Sc*Sc) / 64, 256, 0, stream>>>(adj, sm, A0, wadj);

    // 3) R = X @ [W0 | W1a | Wout]^T  (M=1536, N=600, K=300)
    mgemm<2,0,0,0,0><<<dim3(19, 48, 1), 256, 0, stream>>>(
        X, Dc, 0, W0, 300, 0, W1, Wout,
        nullptr, 0, 0, nullptr, 0.f, nullptr, nullptr,
        R, 600, 0, MT, 600, Dc);

    // 4) G0 = relu(A0 @ P0 + P0 + 2*b0)  (batched; M=384, N=150, K=384)
    mgemm<0,0,1,1,1><<<dim3(5, 12, Bc), 256, 0, stream>>>(
        A0, Sc, AS, R, 600, RS, nullptr, nullptr,
        R, 600, RS, b0, 2.0f, nullptr, nullptr,
        Gbuf, Dc, GS, Sc, HDc, Sc);

    // 5) s1/s2 row reductions of G0
    s12k<<<MT / 4, 256, 0, stream>>>(Gbuf, sm, s12);

    // 6) P1 = Q1 + G0 @ W1b^T  (flat; M=1536, N=150, K=150; in-place R[:,150:300])
    mgemm<1,0,1,0,0><<<dim3(5, 48, 1), 256, 0, stream>>>(
        Gbuf, Dc, 0, W1 + Dc, Dc + HDc, 0, nullptr, nullptr,
        R + HDc, 600, 0, nullptr, 0.f, nullptr, nullptr,
        R + HDc, 600, 0, MT, HDc, HDc);

    // 7) G1 = relu(A1 @ P1 + P1 + 2*b1); A1 fused from wadj+s12 (batched)
    mgemm<0,1,1,1,1><<<dim3(5, 12, Bc), 256, 0, stream>>>(
        wadj, Sc, AS, R + HDc, 600, RS, nullptr, nullptr,
        R + HDc, 600, RS, b1, 2.0f, s12, sm,
        Gbuf + HDc, Dc, GS, Sc, HDc, Sc);

    // 8) out = [G0|G1] @ Wout^T + X@Wout^T + bout  (M=1536, N=300, K=300)
    mgemm<1,0,1,1,0><<<dim3(10, 48, 1), 256, 0, stream>>>(
        Gbuf, Dc, 0, Wout, Dc, 0, nullptr, nullptr,
        R + 2*HDc, 600, 0, bout, 1.0f, nullptr, nullptr,
        out, Dc, 0, MT, Dc, Dc);
}